// Round 5
// baseline (1141.840 us; speedup 1.0000x reference)
//
#include <hip/hip_runtime.h>

#define N_NODES 100000
#define N_EDGES 2500000
#define DIM 32
#define N_REL 6
#define N_BASES 4
#define N_SEG (N_NODES * N_REL)           // 600000 (dst,rel) segments
#define RI 224                             // 6*32 relation sums + 32 self (root)
#define RI_PAD 228                         // Wt row stride (floats)
#define CB 196                             // coarse buckets: dst>>9 (512 nodes each; last=160)
#define CNODES 512
#define CSEG (CNODES * N_REL)              // 3072 fine segments per coarse bucket
#define CAP 72                             // LDS staging capacity per bucket (entries)
#define FLUSH 64                           // flush quantum (256 B)
#define PA_BLOCKS 128
#define LAYER_BLOCKS 3125                  // 32 nodes per block

// ---------------- coarse histogram -------------------------------------------
__global__ __launch_bounds__(1024) void bhist_kernel(const int* __restrict__ dst,
                                                     int* __restrict__ bcnt) {
  __shared__ int h[CB];
  for (int i = threadIdx.x; i < CB; i += 1024) h[i] = 0;
  __syncthreads();
  int stride = gridDim.x * 1024;
  for (int e = blockIdx.x * 1024 + threadIdx.x; e < N_EDGES; e += stride)
    atomicAdd(&h[dst[e] >> 9], 1);
  __syncthreads();
  for (int i = threadIdx.x; i < CB; i += 1024)
    if (h[i]) atomicAdd(&bcnt[i], h[i]);
}

// ---------------- coarse scan (single block) ----------------------------------
__global__ __launch_bounds__(256) void bscan_kernel(const int* __restrict__ bcnt,
                                                    int* __restrict__ bOffs,
                                                    int* __restrict__ cursorA) {
  __shared__ int ts[256];
  int t = threadIdx.x;
  int v = (t < CB) ? bcnt[t] : 0;
  ts[t] = v;
  __syncthreads();
  for (int off = 1; off < 256; off <<= 1) {
    int u = (t >= off) ? ts[t - off] : 0;
    __syncthreads();
    ts[t] += u;
    __syncthreads();
  }
  int excl = ts[t] - v;
  if (t < CB) { bOffs[t] = excl; cursorA[t] = excl; }
  if (t == CB - 1) bOffs[CB] = N_EDGES;
}

// ------- phase A: LDS-chunked partition into coarse buckets (clean writes) ----
// payload: src(17b)<<12 | dst_low9<<3 | et(3b)
__global__ __launch_bounds__(1024) void phaseA_kernel(const int* __restrict__ src,
                                                      const int* __restrict__ dst,
                                                      const int* __restrict__ et,
                                                      int* __restrict__ cursorA,
                                                      unsigned* __restrict__ packed) {
  __shared__ unsigned stage[CB][CAP];      // 56448 B
  __shared__ int cnt[CB];
  for (int i = threadIdx.x; i < CB; i += 1024) cnt[i] = 0;
  __syncthreads();
  int per = (N_EDGES + PA_BLOCKS - 1) / PA_BLOCKS;
  int bstart = blockIdx.x * per;
  int bend = bstart + per; if (bend > N_EDGES) bend = N_EDGES;
  int wid = threadIdx.x >> 6;
  int lane = threadIdx.x & 63;
  for (int base = bstart; base < bend; base += 1024) {
    int e = base + threadIdx.x;
    int b = -1, pos = -1; unsigned pl = 0;
    if (e < bend) {
      int d = dst[e];
      b = d >> 9;
      pl = ((unsigned)src[e] << 12) | ((unsigned)(d & 511) << 3) | (unsigned)et[e];
      pos = atomicAdd(&cnt[b], 1);
      if (pos < CAP) stage[b][pos] = pl;
    }
    __syncthreads();
    for (int bb = wid; bb < CB; bb += 16) {
      int c = cnt[bb]; if (c > CAP) c = CAP;
      int nflush = (c / FLUSH) * FLUSH;
      if (nflush > 0) {
        int g = 0;
        if (lane == 0) g = atomicAdd(&cursorA[bb], nflush);
        g = __shfl(g, 0);
        for (int k = lane; k < nflush; k += 64)
          packed[g + k] = stage[bb][k];          // 256 B contiguous wave-write
        int rem = c - nflush;                    // <= CAP-FLUSH = 8
        unsigned tmp = (lane < rem) ? stage[bb][nflush + lane] : 0u;
        if (lane < rem) stage[bb][lane] = tmp;
        if (lane == 0) cnt[bb] = rem;
      }
    }
    if (pos >= CAP) {
      int g = atomicAdd(&cursorA[b], 1);
      packed[g] = pl;
    }
    __syncthreads();
  }
  for (int bb = wid; bb < CB; bb += 16) {
    int c = cnt[bb]; if (c > CAP) c = CAP;
    if (c > 0) {
      int g = 0;
      if (lane == 0) g = atomicAdd(&cursorA[bb], c);
      g = __shfl(g, 0);
      for (int k = lane; k < c; k += 64)
        packed[g + k] = stage[bb][k];
    }
  }
}

// ------- phase B: per-coarse-bucket fine sort -> node-major CSR ---------------
// ents[] entry = (src<<7) | et  (row byte-offset + relation, for the layer kernel)
__global__ __launch_bounds__(1024) void phaseB_kernel(const unsigned* __restrict__ packed,
                                                      const int* __restrict__ bOffs,
                                                      int* __restrict__ offs,
                                                      unsigned* __restrict__ ents) {
  __shared__ int scnt[CSEG];     // 12 KB
  __shared__ int sexcl[CSEG];    // 12 KB
  __shared__ int ssc[1024];      // 4 KB
  int b = blockIdx.x;
  int t = threadIdx.x;
  int beg = bOffs[b], end = bOffs[b + 1];
  for (int i = t; i < CSEG; i += 1024) scnt[i] = 0;
  __syncthreads();
  for (int i = beg + t; i < end; i += 1024) {
    unsigned pl = packed[i];
    int ls = (int)((pl >> 3) & 511u) * N_REL + (int)(pl & 7u);
    atomicAdd(&scnt[ls], 1);
  }
  __syncthreads();
  int b3 = t * 3;                // 3072 = 1024*3
  int a0 = scnt[b3], a1 = scnt[b3 + 1], a2 = scnt[b3 + 2];
  int s = a0 + a1 + a2;
  ssc[t] = s;
  __syncthreads();
  for (int off = 1; off < 1024; off <<= 1) {
    int u = (t >= off) ? ssc[t - off] : 0;
    __syncthreads();
    ssc[t] += u;
    __syncthreads();
  }
  int excl = ssc[t] - s;
  sexcl[b3] = excl; sexcl[b3 + 1] = excl + a0; sexcl[b3 + 2] = excl + a0 + a1;
#pragma unroll
  for (int k = 0; k < 3; ++k) {
    int ls = b3 + k;
    int gseg = b * CSEG + ls;
    if (gseg < N_SEG) offs[gseg] = beg + sexcl[ls];
  }
  if (b == 0 && t == 0) offs[N_SEG] = N_EDGES;
  __syncthreads();
  scnt[b3] = 0; scnt[b3 + 1] = 0; scnt[b3 + 2] = 0;
  __syncthreads();
  for (int i = beg + t; i < end; i += 1024) {
    unsigned pl = packed[i];
    int ls = (int)((pl >> 3) & 511u) * N_REL + (int)(pl & 7u);
    int p = atomicAdd(&scnt[ls], 1);
    ents[beg + sexcl[ls] + p] = ((pl >> 12) << 7) | (pl & 7u);
  }
}

// ------------- weights: Wt[o][ri] (transposed, padded), both layers ------------
__global__ void weights_kernel(const float* __restrict__ comp1, const float* __restrict__ basis1,
                               const float* __restrict__ root1,
                               const float* __restrict__ comp2, const float* __restrict__ basis2,
                               const float* __restrict__ root2,
                               float* __restrict__ Wt1, float* __restrict__ Wt2) {
  int idx = blockIdx.x * blockDim.x + threadIdx.x;
  if (idx >= 2 * DIM * RI) return;
  int layer = idx / (DIM * RI);
  int rem = idx - layer * (DIM * RI);
  int o = rem / RI;
  int ri = rem - o * RI;
  const float* comp  = layer ? comp2  : comp1;
  const float* basis = layer ? basis2 : basis1;
  const float* root  = layer ? root2  : root1;
  float val;
  if (ri < N_REL * DIM) {
    int r = ri >> 5, i = ri & 31;
    val = 0.f;
#pragma unroll
    for (int bb = 0; bb < N_BASES; ++bb)
      val += comp[r * N_BASES + bb] * basis[(bb * DIM + i) * DIM + o];
  } else {
    int i = ri - N_REL * DIM;
    val = root[i * DIM + o];
  }
  (layer ? Wt2 : Wt1)[o * RI_PAD + ri] = val;
}

// ------------- fused layer: gather -> LDS-atomic sums -> per-rel dot ----------
template <bool RELU>
__global__ __launch_bounds__(1024) void layer_kernel(const float* __restrict__ x,
                                                     const int* __restrict__ offs,
                                                     const unsigned* __restrict__ ents,
                                                     const float* __restrict__ Wt,
                                                     const float* __restrict__ bias,
                                                     float* __restrict__ y) {
  __shared__ float Wl[DIM * RI_PAD];     // 29184 B
  __shared__ float mbuf[32][RI];         // 28672 B
  for (int j = threadIdx.x; j < DIM * RI_PAD; j += 1024) Wl[j] = Wt[j];
  __syncthreads();                       // only Wl needs cross-wave visibility
  int grp = threadIdx.x >> 5;
  int lane = threadIdx.x & 31;
  int n = blockIdx.x * 32 + grp;
  int base = n * N_REL;
  float selfv = x[(size_t)n * DIM + lane];           // issue early
  int t7 = offs[base + ((lane < 7) ? lane : 0)];
  int b0 = __shfl(t7, 0, 32);
  int b1 = __shfl(t7, 1, 32);
  int b2 = __shfl(t7, 2, 32);
  int b3 = __shfl(t7, 3, 32);
  int b4 = __shfl(t7, 4, 32);
  int b5 = __shfl(t7, 5, 32);
  int b6 = __shfl(t7, 6, 32);
  float* mrow = mbuf[grp];
#pragma unroll
  for (int i = 0; i < 7; ++i) mrow[i * 32 + lane] = 0.f;   // own-wave order ok
  unsigned L4 = (unsigned)(lane << 2);
  const char* xb = (const char*)x;
  for (int chunk = b0; chunk < b6; chunk += 32) {
    int myp = chunk + lane;
    unsigned en0 = ents[(myp < b6) ? myp : (b6 - 1)];      // 1 coalesced load / 32 edges
    int m = b6 - chunk;                                    // group-uniform
#pragma unroll
    for (int e = 0; e < 32; e += 8) {
      if (e < m) {
        unsigned q0 = __shfl(en0, e + 0, 32), q1 = __shfl(en0, e + 1, 32);
        unsigned q2 = __shfl(en0, e + 2, 32), q3 = __shfl(en0, e + 3, 32);
        unsigned q4 = __shfl(en0, e + 4, 32), q5 = __shfl(en0, e + 5, 32);
        unsigned q6 = __shfl(en0, e + 6, 32), q7 = __shfl(en0, e + 7, 32);
        // 8 independent gathers in flight (32-bit offsets)
        float v0 = *(const float*)(xb + ((q0 & ~127u) | L4));
        float v1 = *(const float*)(xb + ((q1 & ~127u) | L4));
        float v2 = *(const float*)(xb + ((q2 & ~127u) | L4));
        float v3 = *(const float*)(xb + ((q3 & ~127u) | L4));
        float v4 = *(const float*)(xb + ((q4 & ~127u) | L4));
        float v5 = *(const float*)(xb + ((q5 & ~127u) | L4));
        float v6 = *(const float*)(xb + ((q6 & ~127u) | L4));
        float v7 = *(const float*)(xb + ((q7 & ~127u) | L4));
        atomicAdd(&mrow[((q0 & 7u) << 5) + lane], v0);
        if (e + 1 < m) atomicAdd(&mrow[((q1 & 7u) << 5) + lane], v1);
        if (e + 2 < m) atomicAdd(&mrow[((q2 & 7u) << 5) + lane], v2);
        if (e + 3 < m) atomicAdd(&mrow[((q3 & 7u) << 5) + lane], v3);
        if (e + 4 < m) atomicAdd(&mrow[((q4 & 7u) << 5) + lane], v4);
        if (e + 5 < m) atomicAdd(&mrow[((q5 & 7u) << 5) + lane], v5);
        if (e + 6 < m) atomicAdd(&mrow[((q6 & 7u) << 5) + lane], v6);
        if (e + 7 < m) atomicAdd(&mrow[((q7 & 7u) << 5) + lane], v7);
      }
    }
  }
  mrow[N_REL * DIM + lane] = selfv;      // slot 6 (never atomic'd)
  // per-relation inverse counts (fold mean into the dot)
  float invc[7];
  invc[0] = (b1 - b0) ? 1.f / (float)(b1 - b0) : 0.f;
  invc[1] = (b2 - b1) ? 1.f / (float)(b2 - b1) : 0.f;
  invc[2] = (b3 - b2) ? 1.f / (float)(b3 - b2) : 0.f;
  invc[3] = (b4 - b3) ? 1.f / (float)(b4 - b3) : 0.f;
  invc[4] = (b5 - b4) ? 1.f / (float)(b5 - b4) : 0.f;
  invc[5] = (b6 - b5) ? 1.f / (float)(b6 - b5) : 0.f;
  invc[6] = 1.f;
  // no barrier: each group reads only its own wave's LDS writes
  float accv = bias[lane];
  const float4* wrow = (const float4*)&Wl[lane * RI_PAD];
  const float4* mv = (const float4*)mrow;
#pragma unroll
  for (int r = 0; r < 7; ++r) {
    float s = 0.f;
#pragma unroll
    for (int cc = 0; cc < 8; ++cc) {
      float4 w = wrow[r * 8 + cc];
      float4 mm = mv[r * 8 + cc];
      s += mm.x * w.x + mm.y * w.y + mm.z * w.z + mm.w * w.w;
    }
    accv += invc[r] * s;
  }
  if (RELU) accv = fmaxf(accv, 0.f);
  y[(size_t)n * DIM + lane] = accv;
}

extern "C" void kernel_launch(void* const* d_in, const int* in_sizes, int n_in,
                              void* d_out, int out_size, void* d_ws, size_t ws_size,
                              hipStream_t stream) {
  const float* embedding = (const float*)d_in[0];
  const int*   ei        = (const int*)d_in[1];     // [2, E]: src row, dst row
  const int*   et        = (const int*)d_in[2];
  const float* comp1  = (const float*)d_in[3];
  const float* basis1 = (const float*)d_in[4];
  const float* root1  = (const float*)d_in[5];
  const float* bias1  = (const float*)d_in[6];
  const float* comp2  = (const float*)d_in[7];
  const float* basis2 = (const float*)d_in[8];
  const float* root2  = (const float*)d_in[9];
  const float* bias2  = (const float*)d_in[10];
  float* out = (float*)d_out;

  const int* src = ei;
  const int* dst = ei + N_EDGES;

  float* ws = (float*)d_ws;
  size_t o = 0;
  float* Wt1 = ws + o; o += DIM * RI_PAD;
  float* Wt2 = ws + o; o += DIM * RI_PAD;
  float* x1  = ws + o; o += (size_t)N_NODES * DIM;
  int* bcnt       = (int*)(ws + o); o += CB;
  int* bOffs      = (int*)(ws + o); o += CB + 1;
  int* cursorA    = (int*)(ws + o); o += CB;
  int* offs       = (int*)(ws + o); o += N_SEG + 1;
  unsigned* packed = (unsigned*)(ws + o); o += N_EDGES;
  unsigned* ents  = (unsigned*)(ws + o); o += N_EDGES;

  hipMemsetAsync(bcnt, 0, CB * sizeof(int), stream);
  bhist_kernel<<<240, 1024, 0, stream>>>(dst, bcnt);
  bscan_kernel<<<1, 256, 0, stream>>>(bcnt, bOffs, cursorA);
  phaseA_kernel<<<PA_BLOCKS, 1024, 0, stream>>>(src, dst, et, cursorA, packed);
  phaseB_kernel<<<CB, 1024, 0, stream>>>(packed, bOffs, offs, ents);
  weights_kernel<<<(2 * DIM * RI + 255) / 256, 256, 0, stream>>>(
      comp1, basis1, root1, comp2, basis2, root2, Wt1, Wt2);

  layer_kernel<true><<<LAYER_BLOCKS, 1024, 0, stream>>>(embedding, offs, ents, Wt1, bias1, x1);
  layer_kernel<false><<<LAYER_BLOCKS, 1024, 0, stream>>>(x1, offs, ents, Wt2, bias2, out);
}

// Round 6
// 442.221 us; speedup vs baseline: 2.5821x; 2.5821x over previous
//
#include <hip/hip_runtime.h>

#define N_NODES 100000
#define N_EDGES 2500000
#define DIM 32
#define N_REL 6
#define N_BASES 4
#define N_SEG (N_NODES * N_REL)           // 600000 (dst,rel) segments
#define RI 224                             // 6*32 relation means + 32 self (root)
#define RI_PAD 228                         // Wt row stride (floats)
#define CB 196                             // coarse buckets: dst>>9 (512 nodes each; last=160)
#define CNODES 512
#define CSEG (CNODES * N_REL)              // 3072 fine segments per coarse bucket
#define CAP 72                             // LDS staging capacity per bucket (entries)
#define FLUSH 64                           // flush quantum (256 B)
#define PA_BLOCKS 128
#define NPB 16                             // nodes per block (1 wave64 per node)

// ---------------- coarse histogram -------------------------------------------
__global__ __launch_bounds__(1024) void bhist_kernel(const int* __restrict__ dst,
                                                     int* __restrict__ bcnt) {
  __shared__ int h[CB];
  for (int i = threadIdx.x; i < CB; i += 1024) h[i] = 0;
  __syncthreads();
  int stride = gridDim.x * 1024;
  for (int e = blockIdx.x * 1024 + threadIdx.x; e < N_EDGES; e += stride)
    atomicAdd(&h[dst[e] >> 9], 1);
  __syncthreads();
  for (int i = threadIdx.x; i < CB; i += 1024)
    if (h[i]) atomicAdd(&bcnt[i], h[i]);
}

// ---------------- coarse scan (single block) ----------------------------------
__global__ __launch_bounds__(256) void bscan_kernel(const int* __restrict__ bcnt,
                                                    int* __restrict__ bOffs,
                                                    int* __restrict__ cursorA) {
  __shared__ int ts[256];
  int t = threadIdx.x;
  int v = (t < CB) ? bcnt[t] : 0;
  ts[t] = v;
  __syncthreads();
  for (int off = 1; off < 256; off <<= 1) {
    int u = (t >= off) ? ts[t - off] : 0;
    __syncthreads();
    ts[t] += u;
    __syncthreads();
  }
  int excl = ts[t] - v;
  if (t < CB) { bOffs[t] = excl; cursorA[t] = excl; }
  if (t == CB - 1) bOffs[CB] = N_EDGES;
}

// ------- phase A: LDS-chunked partition into coarse buckets (clean writes) ----
// payload: src(17b)<<12 | dst_low9<<3 | et(3b)
__global__ __launch_bounds__(1024) void phaseA_kernel(const int* __restrict__ src,
                                                      const int* __restrict__ dst,
                                                      const int* __restrict__ et,
                                                      int* __restrict__ cursorA,
                                                      unsigned* __restrict__ packed) {
  __shared__ unsigned stage[CB][CAP];      // 56448 B
  __shared__ int cnt[CB];
  for (int i = threadIdx.x; i < CB; i += 1024) cnt[i] = 0;
  __syncthreads();
  int per = (N_EDGES + PA_BLOCKS - 1) / PA_BLOCKS;
  int bstart = blockIdx.x * per;
  int bend = bstart + per; if (bend > N_EDGES) bend = N_EDGES;
  int wid = threadIdx.x >> 6;
  int lane = threadIdx.x & 63;
  for (int base = bstart; base < bend; base += 1024) {
    int e = base + threadIdx.x;
    int b = -1, pos = -1; unsigned pl = 0;
    if (e < bend) {
      int d = dst[e];
      b = d >> 9;
      pl = ((unsigned)src[e] << 12) | ((unsigned)(d & 511) << 3) | (unsigned)et[e];
      pos = atomicAdd(&cnt[b], 1);
      if (pos < CAP) stage[b][pos] = pl;
    }
    __syncthreads();
    for (int bb = wid; bb < CB; bb += 16) {
      int c = cnt[bb]; if (c > CAP) c = CAP;
      int nflush = (c / FLUSH) * FLUSH;
      if (nflush > 0) {
        int g = 0;
        if (lane == 0) g = atomicAdd(&cursorA[bb], nflush);
        g = __shfl(g, 0);
        for (int k = lane; k < nflush; k += 64)
          packed[g + k] = stage[bb][k];          // 256 B contiguous wave-write
        int rem = c - nflush;                    // <= CAP-FLUSH = 8
        unsigned tmp = (lane < rem) ? stage[bb][nflush + lane] : 0u;
        if (lane < rem) stage[bb][lane] = tmp;
        if (lane == 0) cnt[bb] = rem;
      }
    }
    if (pos >= CAP) {
      int g = atomicAdd(&cursorA[b], 1);
      packed[g] = pl;
    }
    __syncthreads();
  }
  for (int bb = wid; bb < CB; bb += 16) {
    int c = cnt[bb]; if (c > CAP) c = CAP;
    if (c > 0) {
      int g = 0;
      if (lane == 0) g = atomicAdd(&cursorA[bb], c);
      g = __shfl(g, 0);
      for (int k = lane; k < c; k += 64)
        packed[g + k] = stage[bb][k];
    }
  }
}

// ------- phase B: per-coarse-bucket fine sort -> node-major CSR ---------------
// ents[] entry = src<<7 | et (row byte-offset; et bits unused by consumer)
__global__ __launch_bounds__(1024) void phaseB_kernel(const unsigned* __restrict__ packed,
                                                      const int* __restrict__ bOffs,
                                                      int* __restrict__ offs,
                                                      unsigned* __restrict__ ents) {
  __shared__ int scnt[CSEG];     // 12 KB
  __shared__ int sexcl[CSEG];    // 12 KB
  __shared__ int ssc[1024];      // 4 KB
  int b = blockIdx.x;
  int t = threadIdx.x;
  int beg = bOffs[b], end = bOffs[b + 1];
  for (int i = t; i < CSEG; i += 1024) scnt[i] = 0;
  __syncthreads();
  for (int i = beg + t; i < end; i += 1024) {
    unsigned pl = packed[i];
    int ls = (int)((pl >> 3) & 511u) * N_REL + (int)(pl & 7u);
    atomicAdd(&scnt[ls], 1);
  }
  __syncthreads();
  int b3 = t * 3;                // 3072 = 1024*3
  int a0 = scnt[b3], a1 = scnt[b3 + 1], a2 = scnt[b3 + 2];
  int s = a0 + a1 + a2;
  ssc[t] = s;
  __syncthreads();
  for (int off = 1; off < 1024; off <<= 1) {
    int u = (t >= off) ? ssc[t - off] : 0;
    __syncthreads();
    ssc[t] += u;
    __syncthreads();
  }
  int excl = ssc[t] - s;
  sexcl[b3] = excl; sexcl[b3 + 1] = excl + a0; sexcl[b3 + 2] = excl + a0 + a1;
#pragma unroll
  for (int k = 0; k < 3; ++k) {
    int ls = b3 + k;
    int gseg = b * CSEG + ls;
    if (gseg < N_SEG) offs[gseg] = beg + sexcl[ls];
  }
  if (b == 0 && t == 0) offs[N_SEG] = N_EDGES;
  __syncthreads();
  scnt[b3] = 0; scnt[b3 + 1] = 0; scnt[b3 + 2] = 0;
  __syncthreads();
  for (int i = beg + t; i < end; i += 1024) {
    unsigned pl = packed[i];
    int ls = (int)((pl >> 3) & 511u) * N_REL + (int)(pl & 7u);
    int p = atomicAdd(&scnt[ls], 1);
    ents[beg + sexcl[ls] + p] = ((pl >> 12) << 7) | (pl & 7u);
  }
}

// ------------- weights: Wt[o][ri] (transposed, padded), both layers ------------
__global__ void weights_kernel(const float* __restrict__ comp1, const float* __restrict__ basis1,
                               const float* __restrict__ root1,
                               const float* __restrict__ comp2, const float* __restrict__ basis2,
                               const float* __restrict__ root2,
                               float* __restrict__ Wt1, float* __restrict__ Wt2) {
  int idx = blockIdx.x * blockDim.x + threadIdx.x;
  if (idx >= 2 * DIM * RI) return;
  int layer = idx / (DIM * RI);
  int rem = idx - layer * (DIM * RI);
  int o = rem / RI;
  int ri = rem - o * RI;
  const float* comp  = layer ? comp2  : comp1;
  const float* basis = layer ? basis2 : basis1;
  const float* root  = layer ? root2  : root1;
  float val;
  if (ri < N_REL * DIM) {
    int r = ri >> 5, i = ri & 31;
    val = 0.f;
#pragma unroll
    for (int bb = 0; bb < N_BASES; ++bb)
      val += comp[r * N_BASES + bb] * basis[(bb * DIM + i) * DIM + o];
  } else {
    int i = ri - N_REL * DIM;
    val = root[i * DIM + o];
  }
  (layer ? Wt2 : Wt1)[o * RI_PAD + ri] = val;
}

// ------------- fused layer: one wave64 per node, halves = even/odd edges ------
template <bool RELU>
__global__ __launch_bounds__(1024) void layer_kernel(const float* __restrict__ x,
                                                     const int* __restrict__ offs,
                                                     const unsigned* __restrict__ ents,
                                                     const float* __restrict__ Wt,
                                                     const float* __restrict__ bias,
                                                     float* __restrict__ y) {
  __shared__ float Wl[DIM * RI_PAD];     // 29184 B
  __shared__ float mbuf[NPB][RI];        // 14336 B; total 43520 B -> 2 blocks/CU
  for (int j = threadIdx.x; j < DIM * RI_PAD; j += 1024) Wl[j] = Wt[j];
  __syncthreads();                       // Wl cross-wave; mbuf is per-wave
  int wv = threadIdx.x >> 6;             // wave 0..15, one node each
  int lane = threadIdx.x & 63;
  int half = lane >> 5;                  // even/odd edge stream
  int l5 = lane & 31;                    // feature index
  int n = blockIdx.x * NPB + wv;         // grid exact: 6250*16 = 100000
  int base = n * N_REL;
  float selfv = x[(size_t)n * DIM + l5];
  int t7 = offs[base + ((lane < 7) ? lane : 0)];
  int b0 = __shfl(t7, 0);                // width 64: wave-uniform boundaries
  int b1 = __shfl(t7, 1);
  int b2 = __shfl(t7, 2);
  int b3 = __shfl(t7, 3);
  int b4 = __shfl(t7, 4);
  int b5 = __shfl(t7, 5);
  int b6 = __shfl(t7, 6);
  float a0 = 0.f, a1 = 0.f, a2 = 0.f, a3 = 0.f, a4 = 0.f, a5 = 0.f;
  unsigned L4 = (unsigned)(l5 << 2);
  const char* xb = (const char*)x;
  for (int chunk = b0; chunk < b6; chunk += 32) {   // wave-uniform trip count
    int myp = chunk + l5;
    unsigned en = ents[(myp < b6) ? myp : (b6 - 1)];  // halves load same 128B
    int m = b6 - chunk;                               // wave-uniform
    int ph = chunk + half;                            // this lane's e=0 position
#pragma unroll
    for (int e = 0; e < 32; e += 8) {
      if (e < m) {                                    // uniform branch
        // 4 pair-iterations: lane handles edge e+2i+half
        unsigned q0 = __shfl(en, e + 0 + half, 32);   // bpermute, per-half src
        unsigned q1 = __shfl(en, e + 2 + half, 32);
        unsigned q2 = __shfl(en, e + 4 + half, 32);
        unsigned q3 = __shfl(en, e + 6 + half, 32);
        float v0 = *(const float*)(xb + ((q0 & ~127u) | L4));  // 4 full-wave
        float v1 = *(const float*)(xb + ((q1 & ~127u) | L4));  // gathers in
        float v2 = *(const float*)(xb + ((q2 & ~127u) | L4));  // flight
        float v3 = *(const float*)(xb + ((q3 & ~127u) | L4));
        int p0 = ph + e, p1 = p0 + 2, p2 = p0 + 4, p3 = p0 + 6;
        v0 = (p0 - chunk < m) ? v0 : 0.f;             // tail zeroing
        v1 = (p1 - chunk < m) ? v1 : 0.f;
        v2 = (p2 - chunk < m) ? v2 : 0.f;
        v3 = (p3 - chunk < m) ? v3 : 0.f;
        a0 += v0 + v1 + v2 + v3;
        a1 += ((p0 >= b1) ? v0 : 0.f) + ((p1 >= b1) ? v1 : 0.f)
            + ((p2 >= b1) ? v2 : 0.f) + ((p3 >= b1) ? v3 : 0.f);
        a2 += ((p0 >= b2) ? v0 : 0.f) + ((p1 >= b2) ? v1 : 0.f)
            + ((p2 >= b2) ? v2 : 0.f) + ((p3 >= b2) ? v3 : 0.f);
        a3 += ((p0 >= b3) ? v0 : 0.f) + ((p1 >= b3) ? v1 : 0.f)
            + ((p2 >= b3) ? v2 : 0.f) + ((p3 >= b3) ? v3 : 0.f);
        a4 += ((p0 >= b4) ? v0 : 0.f) + ((p1 >= b4) ? v1 : 0.f)
            + ((p2 >= b4) ? v2 : 0.f) + ((p3 >= b4) ? v3 : 0.f);
        a5 += ((p0 >= b5) ? v0 : 0.f) + ((p1 >= b5) ? v1 : 0.f)
            + ((p2 >= b5) ? v2 : 0.f) + ((p3 >= b5) ? v3 : 0.f);
      }
    }
  }
  // combine even/odd halves (width-64 xor-swap)
  a0 += __shfl_xor(a0, 32);
  a1 += __shfl_xor(a1, 32);
  a2 += __shfl_xor(a2, 32);
  a3 += __shfl_xor(a3, 32);
  a4 += __shfl_xor(a4, 32);
  a5 += __shfl_xor(a5, 32);
  float* mrow = mbuf[wv];
  if (half == 0) {
    int c0 = b1 - b0, c1 = b2 - b1, c2 = b3 - b2;
    int c3 = b4 - b3, c4 = b5 - b4, c5 = b6 - b5;
    float s0 = a0 - a1, s1 = a1 - a2, s2 = a2 - a3;
    float s3 = a3 - a4, s4 = a4 - a5, s5 = a5;
    mrow[0 * 32 + l5] = c0 ? s0 / (float)c0 : 0.f;
    mrow[1 * 32 + l5] = c1 ? s1 / (float)c1 : 0.f;
    mrow[2 * 32 + l5] = c2 ? s2 / (float)c2 : 0.f;
    mrow[3 * 32 + l5] = c3 ? s3 / (float)c3 : 0.f;
    mrow[4 * 32 + l5] = c4 ? s4 / (float)c4 : 0.f;
    mrow[5 * 32 + l5] = c5 ? s5 / (float)c5 : 0.f;
    mrow[6 * 32 + l5] = selfv;
  }
  __builtin_amdgcn_wave_barrier();       // same-wave DS order; no block barrier
  // dot: half0 -> rel blocks 0..3, half1 -> 4..6; o = l5
  float accv = half ? 0.f : bias[l5];
  const float4* wrow = (const float4*)&Wl[l5 * RI_PAD];
  const float4* mv = (const float4*)mrow;
#pragma unroll
  for (int rr = 0; rr < 4; ++rr) {
    int r = rr + (half << 2);
    if (r < 7) {
      float s = 0.f;
#pragma unroll
      for (int cc = 0; cc < 8; ++cc) {
        float4 w = wrow[r * 8 + cc];
        float4 mm = mv[r * 8 + cc];
        s += mm.x * w.x + mm.y * w.y + mm.z * w.z + mm.w * w.w;
      }
      accv += s;
    }
  }
  accv += __shfl_xor(accv, 32);
  if (half == 0) {
    if (RELU) accv = fmaxf(accv, 0.f);
    y[(size_t)n * DIM + l5] = accv;
  }
}

extern "C" void kernel_launch(void* const* d_in, const int* in_sizes, int n_in,
                              void* d_out, int out_size, void* d_ws, size_t ws_size,
                              hipStream_t stream) {
  const float* embedding = (const float*)d_in[0];
  const int*   ei        = (const int*)d_in[1];     // [2, E]: src row, dst row
  const int*   et        = (const int*)d_in[2];
  const float* comp1  = (const float*)d_in[3];
  const float* basis1 = (const float*)d_in[4];
  const float* root1  = (const float*)d_in[5];
  const float* bias1  = (const float*)d_in[6];
  const float* comp2  = (const float*)d_in[7];
  const float* basis2 = (const float*)d_in[8];
  const float* root2  = (const float*)d_in[9];
  const float* bias2  = (const float*)d_in[10];
  float* out = (float*)d_out;

  const int* src = ei;
  const int* dst = ei + N_EDGES;

  float* ws = (float*)d_ws;
  size_t o = 0;
  float* Wt1 = ws + o; o += DIM * RI_PAD;
  float* Wt2 = ws + o; o += DIM * RI_PAD;
  float* x1  = ws + o; o += (size_t)N_NODES * DIM;
  int* bcnt       = (int*)(ws + o); o += CB;
  int* bOffs      = (int*)(ws + o); o += CB + 1;
  int* cursorA    = (int*)(ws + o); o += CB;
  int* offs       = (int*)(ws + o); o += N_SEG + 1;
  unsigned* packed = (unsigned*)(ws + o); o += N_EDGES;
  unsigned* ents  = (unsigned*)(ws + o); o += N_EDGES;

  hipMemsetAsync(bcnt, 0, CB * sizeof(int), stream);
  bhist_kernel<<<240, 1024, 0, stream>>>(dst, bcnt);
  bscan_kernel<<<1, 256, 0, stream>>>(bcnt, bOffs, cursorA);
  phaseA_kernel<<<PA_BLOCKS, 1024, 0, stream>>>(src, dst, et, cursorA, packed);
  phaseB_kernel<<<CB, 1024, 0, stream>>>(packed, bOffs, offs, ents);
  weights_kernel<<<(2 * DIM * RI + 255) / 256, 256, 0, stream>>>(
      comp1, basis1, root1, comp2, basis2, root2, Wt1, Wt2);

  layer_kernel<true><<<N_NODES / NPB, 1024, 0, stream>>>(embedding, offs, ents, Wt1, bias1, x1);
  layer_kernel<false><<<N_NODES / NPB, 1024, 0, stream>>>(x1, offs, ents, Wt2, bias2, out);
}

// Round 7
// 394.967 us; speedup vs baseline: 2.8910x; 1.1196x over previous
//
#include <hip/hip_runtime.h>

#define N_NODES 100000
#define N_EDGES 2500000
#define DIM 32
#define N_REL 6
#define N_BASES 4
#define N_SEG (N_NODES * N_REL)           // 600000 (dst,rel) segments
#define CB 196                             // coarse buckets: dst>>9
#define CNODES 512
#define CSEG (CNODES * N_REL)              // 3072 fine segments per coarse bucket
#define CAP 72                             // LDS staging capacity per bucket (entries)
#define FLUSH 64                           // flush quantum (256 B)
#define PA_BLOCKS 128
#define GH_NODES 160                       // nodes per gemm_h block (100000 = 625*160)

// ---------------- coarse histogram -------------------------------------------
__global__ __launch_bounds__(1024) void bhist_kernel(const int* __restrict__ dst,
                                                     int* __restrict__ bcnt) {
  __shared__ int h[CB];
  for (int i = threadIdx.x; i < CB; i += 1024) h[i] = 0;
  __syncthreads();
  int stride = gridDim.x * 1024;
  for (int e = blockIdx.x * 1024 + threadIdx.x; e < N_EDGES; e += stride)
    atomicAdd(&h[dst[e] >> 9], 1);
  __syncthreads();
  for (int i = threadIdx.x; i < CB; i += 1024)
    if (h[i]) atomicAdd(&bcnt[i], h[i]);
}

// ---------------- coarse scan (single block) ----------------------------------
__global__ __launch_bounds__(256) void bscan_kernel(const int* __restrict__ bcnt,
                                                    int* __restrict__ bOffs,
                                                    int* __restrict__ cursorA) {
  __shared__ int ts[256];
  int t = threadIdx.x;
  int v = (t < CB) ? bcnt[t] : 0;
  ts[t] = v;
  __syncthreads();
  for (int off = 1; off < 256; off <<= 1) {
    int u = (t >= off) ? ts[t - off] : 0;
    __syncthreads();
    ts[t] += u;
    __syncthreads();
  }
  int excl = ts[t] - v;
  if (t < CB) { bOffs[t] = excl; cursorA[t] = excl; }
  if (t == CB - 1) bOffs[CB] = N_EDGES;
}

// ------- phase A: LDS-chunked partition into coarse buckets (clean writes) ----
// payload: src(17b)<<12 | dst_low9<<3 | et(3b)
__global__ __launch_bounds__(1024) void phaseA_kernel(const int* __restrict__ src,
                                                      const int* __restrict__ dst,
                                                      const int* __restrict__ et,
                                                      int* __restrict__ cursorA,
                                                      unsigned* __restrict__ packed) {
  __shared__ unsigned stage[CB][CAP];      // 56448 B
  __shared__ int cnt[CB];
  for (int i = threadIdx.x; i < CB; i += 1024) cnt[i] = 0;
  __syncthreads();
  int per = (N_EDGES + PA_BLOCKS - 1) / PA_BLOCKS;
  int bstart = blockIdx.x * per;
  int bend = bstart + per; if (bend > N_EDGES) bend = N_EDGES;
  int wid = threadIdx.x >> 6;
  int lane = threadIdx.x & 63;
  for (int base = bstart; base < bend; base += 1024) {
    int e = base + threadIdx.x;
    int b = -1, pos = -1; unsigned pl = 0;
    if (e < bend) {
      int d = dst[e];
      b = d >> 9;
      pl = ((unsigned)src[e] << 12) | ((unsigned)(d & 511) << 3) | (unsigned)et[e];
      pos = atomicAdd(&cnt[b], 1);
      if (pos < CAP) stage[b][pos] = pl;
    }
    __syncthreads();
    for (int bb = wid; bb < CB; bb += 16) {
      int c = cnt[bb]; if (c > CAP) c = CAP;
      int nflush = (c / FLUSH) * FLUSH;
      if (nflush > 0) {
        int g = 0;
        if (lane == 0) g = atomicAdd(&cursorA[bb], nflush);
        g = __shfl(g, 0);
        for (int k = lane; k < nflush; k += 64)
          packed[g + k] = stage[bb][k];          // 256 B contiguous wave-write
        int rem = c - nflush;                    // <= CAP-FLUSH = 8
        unsigned tmp = (lane < rem) ? stage[bb][nflush + lane] : 0u;
        if (lane < rem) stage[bb][lane] = tmp;
        if (lane == 0) cnt[bb] = rem;
      }
    }
    if (pos >= CAP) {
      int g = atomicAdd(&cursorA[b], 1);
      packed[g] = pl;
    }
    __syncthreads();
  }
  for (int bb = wid; bb < CB; bb += 16) {
    int c = cnt[bb]; if (c > CAP) c = CAP;
    if (c > 0) {
      int g = 0;
      if (lane == 0) g = atomicAdd(&cursorA[bb], c);
      g = __shfl(g, 0);
      for (int k = lane; k < c; k += 64)
        packed[g + k] = stage[bb][k];
    }
  }
}

// ------- phase B: per-coarse-bucket fine sort -> CSR + ents(byte-off) + scl ---
__global__ __launch_bounds__(1024) void phaseB_kernel(const unsigned* __restrict__ packed,
                                                      const int* __restrict__ bOffs,
                                                      int* __restrict__ offs,
                                                      unsigned* __restrict__ ents,
                                                      float* __restrict__ scl) {
  __shared__ int scnt[CSEG];     // 12 KB
  __shared__ int sexcl[CSEG];    // 12 KB
  __shared__ float sinv[CSEG];   // 12 KB
  __shared__ int ssc[1024];      // 4 KB
  int b = blockIdx.x;
  int t = threadIdx.x;
  int beg = bOffs[b], end = bOffs[b + 1];
  for (int i = t; i < CSEG; i += 1024) scnt[i] = 0;
  __syncthreads();
  for (int i = beg + t; i < end; i += 1024) {
    unsigned pl = packed[i];
    int ls = (int)((pl >> 3) & 511u) * N_REL + (int)(pl & 7u);
    atomicAdd(&scnt[ls], 1);
  }
  __syncthreads();
  int b3 = t * 3;                // 3072 = 1024*3
  int a0 = scnt[b3], a1 = scnt[b3 + 1], a2 = scnt[b3 + 2];
  sinv[b3]     = a0 ? 1.f / (float)a0 : 0.f;
  sinv[b3 + 1] = a1 ? 1.f / (float)a1 : 0.f;
  sinv[b3 + 2] = a2 ? 1.f / (float)a2 : 0.f;
  int s = a0 + a1 + a2;
  ssc[t] = s;
  __syncthreads();
  for (int off = 1; off < 1024; off <<= 1) {
    int u = (t >= off) ? ssc[t - off] : 0;
    __syncthreads();
    ssc[t] += u;
    __syncthreads();
  }
  int excl = ssc[t] - s;
  sexcl[b3] = excl; sexcl[b3 + 1] = excl + a0; sexcl[b3 + 2] = excl + a0 + a1;
#pragma unroll
  for (int k = 0; k < 3; ++k) {
    int ls = b3 + k;
    int gseg = b * CSEG + ls;
    if (gseg < N_SEG) offs[gseg] = beg + sexcl[ls];
  }
  if (b == 0 && t == 0) offs[N_SEG] = N_EDGES;
  __syncthreads();
  scnt[b3] = 0; scnt[b3 + 1] = 0; scnt[b3 + 2] = 0;
  __syncthreads();
  for (int i = beg + t; i < end; i += 1024) {
    unsigned pl = packed[i];
    int ls = (int)((pl >> 3) & 511u) * N_REL + (int)(pl & 7u);
    int p = atomicAdd(&scnt[ls], 1);
    int pos = beg + sexcl[ls] + p;
    unsigned sr = pl >> 12, rr = pl & 7u;
    ents[pos] = (rr * (unsigned)N_NODES + sr) << 7;   // byte offset into h
    scl[pos] = sinv[ls];                              // 1/count (mean weight)
  }
}

// ------------- weights: Wf[r][i][o], r=0..5 basis-combined, r=6 root ----------
__global__ void weights_kernel(const float* __restrict__ comp1, const float* __restrict__ basis1,
                               const float* __restrict__ root1,
                               const float* __restrict__ comp2, const float* __restrict__ basis2,
                               const float* __restrict__ root2,
                               float* __restrict__ Wf1, float* __restrict__ Wf2) {
  int idx = blockIdx.x * blockDim.x + threadIdx.x;
  if (idx >= 2 * 7 * DIM * DIM) return;
  int layer = idx / (7 * DIM * DIM);
  int rem = idx - layer * (7 * DIM * DIM);
  int r = rem / (DIM * DIM);
  int io = rem - r * (DIM * DIM);        // i*32+o
  const float* comp  = layer ? comp2  : comp1;
  const float* basis = layer ? basis2 : basis1;
  const float* root  = layer ? root2  : root1;
  float val;
  if (r < 6) {
    val = 0.f;
#pragma unroll
    for (int bb = 0; bb < N_BASES; ++bb)
      val += comp[r * N_BASES + bb] * basis[bb * DIM * DIM + io];
  } else {
    val = root[io];
  }
  (layer ? Wf2 : Wf1)[rem] = val;
}

// ------------- h precompute: h[r][n][o] = sum_i x[n][i] * Wf[r][i][o] ---------
__global__ __launch_bounds__(1024) void gemm_h_kernel(const float* __restrict__ x,
                                                      const float* __restrict__ Wf,
                                                      float* __restrict__ h) {
  __shared__ float mst[GH_NODES * 36];   // padded stride 36 (16B-aligned rows)
  int r = blockIdx.y;
  int n0 = blockIdx.x * GH_NODES;
  for (int t = threadIdx.x; t < GH_NODES * 32; t += 1024)
    mst[(t >> 5) * 36 + (t & 31)] = x[(size_t)n0 * 32 + t];
  int lane = threadIdx.x & 63, wv = threadIdx.x >> 6;
  int half = lane >> 5, l5 = lane & 31;
  const float* Wr = Wf + r * 1024;
  float w[32];
#pragma unroll
  for (int i = 0; i < 32; ++i) w[i] = Wr[i * 32 + l5];   // broadcast, L1-hot
  __syncthreads();
  float* hr = h + (size_t)r * N_NODES * 32;
#pragma unroll
  for (int k = 0; k < 5; ++k) {
    int nl = wv * 10 + k * 2 + half;                      // 2 nodes per wave
    const float4* mrow = (const float4*)&mst[nl * 36];
    float acc = 0.f;
#pragma unroll
    for (int i4 = 0; i4 < 8; ++i4) {
      float4 xx = mrow[i4];                               // LDS broadcast read
      acc = fmaf(xx.x, w[i4 * 4 + 0], acc);
      acc = fmaf(xx.y, w[i4 * 4 + 1], acc);
      acc = fmaf(xx.z, w[i4 * 4 + 2], acc);
      acc = fmaf(xx.w, w[i4 * 4 + 3], acc);
    }
    hr[(size_t)(n0 + nl) * 32 + l5] = acc;                // coalesced store
  }
}

// ------------- consume: per-node scaled gather-sum over edges -----------------
template <bool RELU>
__global__ __launch_bounds__(1024) void consume_kernel(const float* __restrict__ h,
                                                       const int* __restrict__ offs,
                                                       const unsigned* __restrict__ ents,
                                                       const float* __restrict__ scl,
                                                       const float* __restrict__ bias,
                                                       float* __restrict__ y) {
  int wv = threadIdx.x >> 6, lane = threadIdx.x & 63;
  int half = lane >> 5, l5 = lane & 31;
  int n = blockIdx.x * 16 + wv;          // grid exact: 6250*16 = 100000
  int b0 = offs[n * N_REL], b6 = offs[n * N_REL + 6];
  unsigned L4 = (unsigned)(l5 << 2);
  const char* hb = (const char*)h;
  float acc = 0.f;
  for (int chunk = b0; chunk < b6; chunk += 32) {
    int myp = chunk + l5;
    int cl = (myp < b6) ? myp : (b6 - 1);
    unsigned en = ents[cl];              // coalesced, both halves same 128B
    float sc = scl[cl];
    sc = (myp < b6) ? sc : 0.f;          // tail-zero once per chunk
    int m = b6 - chunk;                  // wave-uniform
#pragma unroll
    for (int e = 0; e < 32; e += 8) {
      if (e < m) {                       // uniform branch
        unsigned q0 = __shfl(en, e + 0 + half, 32), q1 = __shfl(en, e + 2 + half, 32);
        unsigned q2 = __shfl(en, e + 4 + half, 32), q3 = __shfl(en, e + 6 + half, 32);
        float s0 = __shfl(sc, e + 0 + half, 32), s1 = __shfl(sc, e + 2 + half, 32);
        float s2 = __shfl(sc, e + 4 + half, 32), s3 = __shfl(sc, e + 6 + half, 32);
        float v0 = *(const float*)(hb + (q0 | L4));   // 4 full-wave gathers
        float v1 = *(const float*)(hb + (q1 | L4));
        float v2 = *(const float*)(hb + (q2 | L4));
        float v3 = *(const float*)(hb + (q3 | L4));
        acc = fmaf(s0, v0, acc);
        acc = fmaf(s1, v1, acc);
        acc = fmaf(s2, v2, acc);
        acc = fmaf(s3, v3, acc);
      }
    }
  }
  acc += __shfl_xor(acc, 32);            // combine even/odd edge streams
  float res = acc + h[((size_t)6 * N_NODES + n) * 32 + l5] + bias[l5];  // root + bias
  if (RELU) res = fmaxf(res, 0.f);
  if (half == 0) y[(size_t)n * 32 + l5] = res;
}

extern "C" void kernel_launch(void* const* d_in, const int* in_sizes, int n_in,
                              void* d_out, int out_size, void* d_ws, size_t ws_size,
                              hipStream_t stream) {
  const float* embedding = (const float*)d_in[0];
  const int*   ei        = (const int*)d_in[1];     // [2, E]: src row, dst row
  const int*   et        = (const int*)d_in[2];
  const float* comp1  = (const float*)d_in[3];
  const float* basis1 = (const float*)d_in[4];
  const float* root1  = (const float*)d_in[5];
  const float* bias1  = (const float*)d_in[6];
  const float* comp2  = (const float*)d_in[7];
  const float* basis2 = (const float*)d_in[8];
  const float* root2  = (const float*)d_in[9];
  const float* bias2  = (const float*)d_in[10];
  float* out = (float*)d_out;

  const int* src = ei;
  const int* dst = ei + N_EDGES;

  float* ws = (float*)d_ws;
  size_t o = 0;
  float* Wf1 = ws + o; o += 7 * DIM * DIM;
  float* Wf2 = ws + o; o += 7 * DIM * DIM;
  float* x1  = ws + o; o += (size_t)N_NODES * DIM;
  float* h   = ws + o; o += (size_t)7 * N_NODES * DIM;   // 89.6 MB
  int* offs       = (int*)(ws + o); o += N_SEG + 1;
  unsigned* ents  = (unsigned*)(ws + o); o += N_EDGES;
  float* scl      = (float*)(ws + o); o += N_EDGES;
  int* bcnt       = (int*)(ws + o); o += CB;
  int* bOffs      = (int*)(ws + o); o += CB + 1;
  int* cursorA    = (int*)(ws + o); o += CB;
  unsigned* packed = (unsigned*)h;       // alias: dead before gemm_h writes h

  hipMemsetAsync(bcnt, 0, CB * sizeof(int), stream);
  bhist_kernel<<<240, 1024, 0, stream>>>(dst, bcnt);
  bscan_kernel<<<1, 256, 0, stream>>>(bcnt, bOffs, cursorA);
  phaseA_kernel<<<PA_BLOCKS, 1024, 0, stream>>>(src, dst, et, cursorA, packed);
  phaseB_kernel<<<CB, 1024, 0, stream>>>(packed, bOffs, offs, ents, scl);
  weights_kernel<<<(2 * 7 * DIM * DIM + 255) / 256, 256, 0, stream>>>(
      comp1, basis1, root1, comp2, basis2, root2, Wf1, Wf2);

  // layer 1
  gemm_h_kernel<<<dim3(N_NODES / GH_NODES, 7), 1024, 0, stream>>>(embedding, Wf1, h);
  consume_kernel<true><<<N_NODES / 16, 1024, 0, stream>>>(h, offs, ents, scl, bias1, x1);
  // layer 2
  gemm_h_kernel<<<dim3(N_NODES / GH_NODES, 7), 1024, 0, stream>>>(x1, Wf2, h);
  consume_kernel<false><<<N_NODES / 16, 1024, 0, stream>>>(h, offs, ents, scl, bias2, out);
}

// Round 8
// 300.797 us; speedup vs baseline: 3.7960x; 1.3131x over previous
//
#include <hip/hip_runtime.h>

#define N_NODES 100000
#define N_EDGES 2500000
#define DIM 32
#define N_REL 6
#define N_BASES 4
#define N_SEG (N_NODES * N_REL)           // 600000 (dst,rel) segments
#define CB 196                             // coarse buckets: dst>>9
#define CNODES 512
#define CSEG (CNODES * N_REL)              // 3072 fine segments per coarse bucket
#define NBLK 256                           // partition blocks (1/CU)
#define SCAN_N (CB * NBLK)                 // 50176 = 1024 * 49
#define NITEM 49
#define GH_NODES 160                       // nodes per gemm_h block (100000 = 625*160)

// ---- pass 1: per-block bucket histogram -> cnt2[bucket*NBLK + block] ---------
__global__ __launch_bounds__(1024) void hist2_kernel(const int* __restrict__ dst,
                                                     int* __restrict__ cnt2) {
  __shared__ int h[CB];
  int t = threadIdx.x;
  for (int i = t; i < CB; i += 1024) h[i] = 0;
  __syncthreads();
  int per = (N_EDGES + NBLK - 1) / NBLK;
  int bstart = blockIdx.x * per;
  int bend = bstart + per; if (bend > N_EDGES) bend = N_EDGES;
  for (int e = bstart + t; e < bend; e += 1024)
    atomicAdd(&h[dst[e] >> 9], 1);
  __syncthreads();
  for (int i = t; i < CB; i += 1024)
    cnt2[i * NBLK + blockIdx.x] = h[i];
}

// ---- pass 2: exclusive scan of cnt2 (bucket-major) + bOffs -------------------
__global__ __launch_bounds__(1024) void scan2_kernel(int* __restrict__ cnt2,
                                                     int* __restrict__ bOffs) {
  __shared__ int ts[1024];
  int t = threadIdx.x;
  int base = t * NITEM;
  int loc[NITEM];
  int s = 0;
#pragma unroll
  for (int k = 0; k < NITEM; ++k) { loc[k] = s; s += cnt2[base + k]; }
  ts[t] = s;
  __syncthreads();
  for (int off = 1; off < 1024; off <<= 1) {
    int u = (t >= off) ? ts[t - off] : 0;
    __syncthreads();
    ts[t] += u;
    __syncthreads();
  }
  int excl = ts[t] - s;
#pragma unroll
  for (int k = 0; k < NITEM; ++k) {
    int idx = base + k;
    int v = excl + loc[k];
    cnt2[idx] = v;
    if ((idx & (NBLK - 1)) == 0) bOffs[idx / NBLK] = v;   // bucket boundary
  }
  if (t == 0) bOffs[CB] = N_EDGES;
}

// ---- pass 3: scatter into private (bucket,block) runs ------------------------
// payload: src(17b)<<12 | dst_low9<<3 | et(3b)
__global__ __launch_bounds__(1024) void scatter2_kernel(const int* __restrict__ src,
                                                        const int* __restrict__ dst,
                                                        const int* __restrict__ et,
                                                        const int* __restrict__ cnt2,
                                                        unsigned* __restrict__ packed) {
  __shared__ int sbase[CB];
  __shared__ int lcnt[CB];
  int t = threadIdx.x;
  for (int i = t; i < CB; i += 1024) {
    sbase[i] = cnt2[i * NBLK + blockIdx.x];
    lcnt[i] = 0;
  }
  __syncthreads();
  int per = (N_EDGES + NBLK - 1) / NBLK;
  int bstart = blockIdx.x * per;
  int bend = bstart + per; if (bend > N_EDGES) bend = N_EDGES;
  for (int e = bstart + t; e < bend; e += 1024) {
    int d = dst[e];
    int b = d >> 9;
    unsigned pl = ((unsigned)src[e] << 12) | ((unsigned)(d & 511) << 3) | (unsigned)et[e];
    int p = atomicAdd(&lcnt[b], 1);
    packed[sbase[b] + p] = pl;     // run private to this block -> clean lines
  }
}

// ------- phase B: per-coarse-bucket fine sort -> CSR + ents(byte-off) + scl ---
__global__ __launch_bounds__(1024) void phaseB_kernel(const unsigned* __restrict__ packed,
                                                      const int* __restrict__ bOffs,
                                                      int* __restrict__ offs,
                                                      unsigned* __restrict__ ents,
                                                      float* __restrict__ scl) {
  __shared__ int scnt[CSEG];     // 12 KB
  __shared__ int sexcl[CSEG];    // 12 KB
  __shared__ float sinv[CSEG];   // 12 KB
  __shared__ int ssc[1024];      // 4 KB
  int b = blockIdx.x;
  int t = threadIdx.x;
  int beg = bOffs[b], end = bOffs[b + 1];
  for (int i = t; i < CSEG; i += 1024) scnt[i] = 0;
  __syncthreads();
  for (int i = beg + t; i < end; i += 1024) {
    unsigned pl = packed[i];
    int ls = (int)((pl >> 3) & 511u) * N_REL + (int)(pl & 7u);
    atomicAdd(&scnt[ls], 1);
  }
  __syncthreads();
  int b3 = t * 3;                // 3072 = 1024*3
  int a0 = scnt[b3], a1 = scnt[b3 + 1], a2 = scnt[b3 + 2];
  sinv[b3]     = a0 ? 1.f / (float)a0 : 0.f;
  sinv[b3 + 1] = a1 ? 1.f / (float)a1 : 0.f;
  sinv[b3 + 2] = a2 ? 1.f / (float)a2 : 0.f;
  int s = a0 + a1 + a2;
  ssc[t] = s;
  __syncthreads();
  for (int off = 1; off < 1024; off <<= 1) {
    int u = (t >= off) ? ssc[t - off] : 0;
    __syncthreads();
    ssc[t] += u;
    __syncthreads();
  }
  int excl = ssc[t] - s;
  sexcl[b3] = excl; sexcl[b3 + 1] = excl + a0; sexcl[b3 + 2] = excl + a0 + a1;
#pragma unroll
  for (int k = 0; k < 3; ++k) {
    int ls = b3 + k;
    int gseg = b * CSEG + ls;
    if (gseg < N_SEG) offs[gseg] = beg + sexcl[ls];
  }
  if (b == 0 && t == 0) offs[N_SEG] = N_EDGES;
  __syncthreads();
  scnt[b3] = 0; scnt[b3 + 1] = 0; scnt[b3 + 2] = 0;
  __syncthreads();
  for (int i = beg + t; i < end; i += 1024) {
    unsigned pl = packed[i];
    int ls = (int)((pl >> 3) & 511u) * N_REL + (int)(pl & 7u);
    int p = atomicAdd(&scnt[ls], 1);
    int pos = beg + sexcl[ls] + p;
    unsigned sr = pl >> 12, rr = pl & 7u;
    ents[pos] = (rr * (unsigned)N_NODES + sr) << 7;   // byte offset into h
    scl[pos] = sinv[ls];                              // 1/count (mean weight)
  }
}

// ------------- weights: Wf[r][i][o], r=0..5 basis-combined, r=6 root ----------
__global__ void weights_kernel(const float* __restrict__ comp1, const float* __restrict__ basis1,
                               const float* __restrict__ root1,
                               const float* __restrict__ comp2, const float* __restrict__ basis2,
                               const float* __restrict__ root2,
                               float* __restrict__ Wf1, float* __restrict__ Wf2) {
  int idx = blockIdx.x * blockDim.x + threadIdx.x;
  if (idx >= 2 * 7 * DIM * DIM) return;
  int layer = idx / (7 * DIM * DIM);
  int rem = idx - layer * (7 * DIM * DIM);
  int r = rem / (DIM * DIM);
  int io = rem - r * (DIM * DIM);        // i*32+o
  const float* comp  = layer ? comp2  : comp1;
  const float* basis = layer ? basis2 : basis1;
  const float* root  = layer ? root2  : root1;
  float val;
  if (r < 6) {
    val = 0.f;
#pragma unroll
    for (int bb = 0; bb < N_BASES; ++bb)
      val += comp[r * N_BASES + bb] * basis[bb * DIM * DIM + io];
  } else {
    val = root[io];
  }
  (layer ? Wf2 : Wf1)[rem] = val;
}

// ------------- h precompute: h[r][n][o] = sum_i x[n][i] * Wf[r][i][o] ---------
__global__ __launch_bounds__(1024) void gemm_h_kernel(const float* __restrict__ x,
                                                      const float* __restrict__ Wf,
                                                      float* __restrict__ h) {
  __shared__ float mst[GH_NODES * 36];   // padded stride 36 (16B-aligned rows)
  int r = blockIdx.y;
  int n0 = blockIdx.x * GH_NODES;
  for (int t = threadIdx.x; t < GH_NODES * 32; t += 1024)
    mst[(t >> 5) * 36 + (t & 31)] = x[(size_t)n0 * 32 + t];
  int lane = threadIdx.x & 63, wv = threadIdx.x >> 6;
  int half = lane >> 5, l5 = lane & 31;
  const float* Wr = Wf + r * 1024;
  float w[32];
#pragma unroll
  for (int i = 0; i < 32; ++i) w[i] = Wr[i * 32 + l5];   // broadcast, L1-hot
  __syncthreads();
  float* hr = h + (size_t)r * N_NODES * 32;
#pragma unroll
  for (int k = 0; k < 5; ++k) {
    int nl = wv * 10 + k * 2 + half;                      // 2 nodes per wave
    const float4* mrow = (const float4*)&mst[nl * 36];
    float acc = 0.f;
#pragma unroll
    for (int i4 = 0; i4 < 8; ++i4) {
      float4 xx = mrow[i4];                               // LDS broadcast read
      acc = fmaf(xx.x, w[i4 * 4 + 0], acc);
      acc = fmaf(xx.y, w[i4 * 4 + 1], acc);
      acc = fmaf(xx.z, w[i4 * 4 + 2], acc);
      acc = fmaf(xx.w, w[i4 * 4 + 3], acc);
    }
    hr[(size_t)(n0 + nl) * 32 + l5] = acc;                // coalesced store
  }
}

// ------------- consume: per-node scaled gather-sum over edges -----------------
template <bool RELU>
__global__ __launch_bounds__(1024) void consume_kernel(const float* __restrict__ h,
                                                       const int* __restrict__ offs,
                                                       const unsigned* __restrict__ ents,
                                                       const float* __restrict__ scl,
                                                       const float* __restrict__ bias,
                                                       float* __restrict__ y) {
  int wv = threadIdx.x >> 6, lane = threadIdx.x & 63;
  int half = lane >> 5, l5 = lane & 31;
  int n = blockIdx.x * 16 + wv;          // grid exact: 6250*16 = 100000
  int b0 = offs[n * N_REL], b6 = offs[n * N_REL + 6];
  unsigned L4 = (unsigned)(l5 << 2);
  const char* hb = (const char*)h;
  float acc = 0.f;
  for (int chunk = b0; chunk < b6; chunk += 32) {
    int myp = chunk + l5;
    int cl = (myp < b6) ? myp : (b6 - 1);
    unsigned en = ents[cl];              // coalesced, both halves same 128B
    float sc = scl[cl];
    sc = (myp < b6) ? sc : 0.f;          // tail-zero once per chunk
    int m = b6 - chunk;                  // wave-uniform
#pragma unroll
    for (int e = 0; e < 32; e += 8) {
      if (e < m) {                       // uniform branch
        unsigned q0 = __shfl(en, e + 0 + half, 32), q1 = __shfl(en, e + 2 + half, 32);
        unsigned q2 = __shfl(en, e + 4 + half, 32), q3 = __shfl(en, e + 6 + half, 32);
        float s0 = __shfl(sc, e + 0 + half, 32), s1 = __shfl(sc, e + 2 + half, 32);
        float s2 = __shfl(sc, e + 4 + half, 32), s3 = __shfl(sc, e + 6 + half, 32);
        float v0 = *(const float*)(hb + (q0 | L4));   // 4 full-wave gathers
        float v1 = *(const float*)(hb + (q1 | L4));
        float v2 = *(const float*)(hb + (q2 | L4));
        float v3 = *(const float*)(hb + (q3 | L4));
        acc = fmaf(s0, v0, acc);
        acc = fmaf(s1, v1, acc);
        acc = fmaf(s2, v2, acc);
        acc = fmaf(s3, v3, acc);
      }
    }
  }
  acc += __shfl_xor(acc, 32);            // combine even/odd edge streams
  float res = acc + h[((size_t)6 * N_NODES + n) * 32 + l5] + bias[l5];  // root + bias
  if (RELU) res = fmaxf(res, 0.f);
  if (half == 0) y[(size_t)n * 32 + l5] = res;
}

extern "C" void kernel_launch(void* const* d_in, const int* in_sizes, int n_in,
                              void* d_out, int out_size, void* d_ws, size_t ws_size,
                              hipStream_t stream) {
  const float* embedding = (const float*)d_in[0];
  const int*   ei        = (const int*)d_in[1];     // [2, E]: src row, dst row
  const int*   et        = (const int*)d_in[2];
  const float* comp1  = (const float*)d_in[3];
  const float* basis1 = (const float*)d_in[4];
  const float* root1  = (const float*)d_in[5];
  const float* bias1  = (const float*)d_in[6];
  const float* comp2  = (const float*)d_in[7];
  const float* basis2 = (const float*)d_in[8];
  const float* root2  = (const float*)d_in[9];
  const float* bias2  = (const float*)d_in[10];
  float* out = (float*)d_out;

  const int* src = ei;
  const int* dst = ei + N_EDGES;

  float* ws = (float*)d_ws;
  size_t o = 0;
  float* Wf1 = ws + o; o += 7 * DIM * DIM;
  float* Wf2 = ws + o; o += 7 * DIM * DIM;
  float* x1  = ws + o; o += (size_t)N_NODES * DIM;
  float* h   = ws + o; o += (size_t)7 * N_NODES * DIM;   // 89.6 MB
  int* offs       = (int*)(ws + o); o += N_SEG + 1;
  unsigned* ents  = (unsigned*)(ws + o); o += N_EDGES;
  float* scl      = (float*)(ws + o); o += N_EDGES;
  int* cnt2       = (int*)(ws + o); o += SCAN_N;
  int* bOffs      = (int*)(ws + o); o += CB + 1;
  unsigned* packed = (unsigned*)h;       // alias: dead before gemm_h writes h

  hist2_kernel<<<NBLK, 1024, 0, stream>>>(dst, cnt2);
  scan2_kernel<<<1, 1024, 0, stream>>>(cnt2, bOffs);
  scatter2_kernel<<<NBLK, 1024, 0, stream>>>(src, dst, et, cnt2, packed);
  phaseB_kernel<<<CB, 1024, 0, stream>>>(packed, bOffs, offs, ents, scl);
  weights_kernel<<<(2 * 7 * DIM * DIM + 255) / 256, 256, 0, stream>>>(
      comp1, basis1, root1, comp2, basis2, root2, Wf1, Wf2);

  // layer 1
  gemm_h_kernel<<<dim3(N_NODES / GH_NODES, 7), 1024, 0, stream>>>(embedding, Wf1, h);
  consume_kernel<true><<<N_NODES / 16, 1024, 0, stream>>>(h, offs, ents, scl, bias1, x1);
  // layer 2
  gemm_h_kernel<<<dim3(N_NODES / GH_NODES, 7), 1024, 0, stream>>>(x1, Wf2, h);
  consume_kernel<false><<<N_NODES / 16, 1024, 0, stream>>>(h, offs, ents, scl, bias2, out);
}

// Round 9
// 283.935 us; speedup vs baseline: 4.0215x; 1.0594x over previous
//
#include <hip/hip_runtime.h>

#define N_NODES 100000
#define N_EDGES 2500000
#define DIM 32
#define N_REL 6
#define N_BASES 4
#define N_SEG (N_NODES * N_REL)           // 600000 (dst,rel) segments
#define CB 196                             // coarse buckets: dst>>9
#define CNODES 512
#define CSEG (CNODES * N_REL)              // 3072 fine segments per coarse bucket
#define NBLK 256                           // partition blocks (1/CU)
#define SCAN_N (CB * NBLK)                 // 50176 = 1024 * 49
#define NITEM 49
#define GH_NODES 160                       // nodes per gemm_h block (100000 = 625*160)

// ---- pass 1: per-block bucket histogram -> cnt2[bucket*NBLK + block] ---------
__global__ __launch_bounds__(1024) void hist2_kernel(const int* __restrict__ dst,
                                                     int* __restrict__ cnt2) {
  __shared__ int h[CB];
  int t = threadIdx.x;
  for (int i = t; i < CB; i += 1024) h[i] = 0;
  __syncthreads();
  int per = (N_EDGES + NBLK - 1) / NBLK;
  int bstart = blockIdx.x * per;
  int bend = bstart + per; if (bend > N_EDGES) bend = N_EDGES;
  for (int e = bstart + t; e < bend; e += 1024)
    atomicAdd(&h[dst[e] >> 9], 1);
  __syncthreads();
  for (int i = t; i < CB; i += 1024)
    cnt2[i * NBLK + blockIdx.x] = h[i];
}

// ---- pass 2: exclusive scan of cnt2 (bucket-major) + bOffs -------------------
__global__ __launch_bounds__(1024) void scan2_kernel(int* __restrict__ cnt2,
                                                     int* __restrict__ bOffs) {
  __shared__ int ts[1024];
  int t = threadIdx.x;
  int base = t * NITEM;
  int loc[NITEM];
  int s = 0;
#pragma unroll
  for (int k = 0; k < NITEM; ++k) { loc[k] = s; s += cnt2[base + k]; }
  ts[t] = s;
  __syncthreads();
  for (int off = 1; off < 1024; off <<= 1) {
    int u = (t >= off) ? ts[t - off] : 0;
    __syncthreads();
    ts[t] += u;
    __syncthreads();
  }
  int excl = ts[t] - s;
#pragma unroll
  for (int k = 0; k < NITEM; ++k) {
    int idx = base + k;
    int v = excl + loc[k];
    cnt2[idx] = v;
    if ((idx & (NBLK - 1)) == 0) bOffs[idx / NBLK] = v;   // bucket boundary
  }
  if (t == 0) bOffs[CB] = N_EDGES;
}

// ---- pass 3: scatter into private (bucket,block) runs ------------------------
// payload: src(17b)<<12 | dst_low9<<3 | et(3b)
__global__ __launch_bounds__(1024) void scatter2_kernel(const int* __restrict__ src,
                                                        const int* __restrict__ dst,
                                                        const int* __restrict__ et,
                                                        const int* __restrict__ cnt2,
                                                        unsigned* __restrict__ packed) {
  __shared__ int sbase[CB];
  __shared__ int lcnt[CB];
  int t = threadIdx.x;
  for (int i = t; i < CB; i += 1024) {
    sbase[i] = cnt2[i * NBLK + blockIdx.x];
    lcnt[i] = 0;
  }
  __syncthreads();
  int per = (N_EDGES + NBLK - 1) / NBLK;
  int bstart = blockIdx.x * per;
  int bend = bstart + per; if (bend > N_EDGES) bend = N_EDGES;
  for (int e = bstart + t; e < bend; e += 1024) {
    int d = dst[e];
    int b = d >> 9;
    unsigned pl = ((unsigned)src[e] << 12) | ((unsigned)(d & 511) << 3) | (unsigned)et[e];
    int p = atomicAdd(&lcnt[b], 1);
    packed[sbase[b] + p] = pl;     // run private to this block -> clean lines
  }
}

// ------- phase B: per-coarse-bucket fine sort -> CSR + (ent,scl) pairs --------
__global__ __launch_bounds__(1024) void phaseB_kernel(const unsigned* __restrict__ packed,
                                                      const int* __restrict__ bOffs,
                                                      int* __restrict__ offs,
                                                      uint2* __restrict__ eps) {
  __shared__ int scnt[CSEG];     // 12 KB
  __shared__ int sexcl[CSEG];    // 12 KB
  __shared__ float sinv[CSEG];   // 12 KB
  __shared__ int ssc[1024];      // 4 KB
  int b = blockIdx.x;
  int t = threadIdx.x;
  int beg = bOffs[b], end = bOffs[b + 1];
  for (int i = t; i < CSEG; i += 1024) scnt[i] = 0;
  __syncthreads();
  for (int i = beg + t; i < end; i += 1024) {
    unsigned pl = packed[i];
    int ls = (int)((pl >> 3) & 511u) * N_REL + (int)(pl & 7u);
    atomicAdd(&scnt[ls], 1);
  }
  __syncthreads();
  int b3 = t * 3;                // 3072 = 1024*3
  int a0 = scnt[b3], a1 = scnt[b3 + 1], a2 = scnt[b3 + 2];
  sinv[b3]     = a0 ? 1.f / (float)a0 : 0.f;
  sinv[b3 + 1] = a1 ? 1.f / (float)a1 : 0.f;
  sinv[b3 + 2] = a2 ? 1.f / (float)a2 : 0.f;
  int s = a0 + a1 + a2;
  ssc[t] = s;
  __syncthreads();
  for (int off = 1; off < 1024; off <<= 1) {
    int u = (t >= off) ? ssc[t - off] : 0;
    __syncthreads();
    ssc[t] += u;
    __syncthreads();
  }
  int excl = ssc[t] - s;
  sexcl[b3] = excl; sexcl[b3 + 1] = excl + a0; sexcl[b3 + 2] = excl + a0 + a1;
#pragma unroll
  for (int k = 0; k < 3; ++k) {
    int ls = b3 + k;
    int gseg = b * CSEG + ls;
    if (gseg < N_SEG) offs[gseg] = beg + sexcl[ls];
  }
  if (b == 0 && t == 0) offs[N_SEG] = N_EDGES;
  __syncthreads();
  scnt[b3] = 0; scnt[b3 + 1] = 0; scnt[b3 + 2] = 0;
  __syncthreads();
  for (int i = beg + t; i < end; i += 1024) {
    unsigned pl = packed[i];
    int ls = (int)((pl >> 3) & 511u) * N_REL + (int)(pl & 7u);
    int p = atomicAdd(&scnt[ls], 1);
    int pos = beg + sexcl[ls] + p;
    unsigned sr = pl >> 12, rr = pl & 7u;
    uint2 v;
    v.x = (rr * (unsigned)N_NODES + sr) << 7;   // byte offset into h
    v.y = __float_as_uint(sinv[ls]);            // 1/count (mean weight)
    eps[pos] = v;
  }
}

// ------------- weights: Wf[r][i][o], r=0..5 basis-combined, r=6 root ----------
__global__ void weights_kernel(const float* __restrict__ comp1, const float* __restrict__ basis1,
                               const float* __restrict__ root1,
                               const float* __restrict__ comp2, const float* __restrict__ basis2,
                               const float* __restrict__ root2,
                               float* __restrict__ Wf1, float* __restrict__ Wf2) {
  int idx = blockIdx.x * blockDim.x + threadIdx.x;
  if (idx >= 2 * 7 * DIM * DIM) return;
  int layer = idx / (7 * DIM * DIM);
  int rem = idx - layer * (7 * DIM * DIM);
  int r = rem / (DIM * DIM);
  int io = rem - r * (DIM * DIM);        // i*32+o
  const float* comp  = layer ? comp2  : comp1;
  const float* basis = layer ? basis2 : basis1;
  const float* root  = layer ? root2  : root1;
  float val;
  if (r < 6) {
    val = 0.f;
#pragma unroll
    for (int bb = 0; bb < N_BASES; ++bb)
      val += comp[r * N_BASES + bb] * basis[bb * DIM * DIM + io];
  } else {
    val = root[io];
  }
  (layer ? Wf2 : Wf1)[rem] = val;
}

// ------------- h precompute: h[r][n][o] = sum_i x[n][i] * Wf[r][i][o] ---------
__global__ __launch_bounds__(1024) void gemm_h_kernel(const float* __restrict__ x,
                                                      const float* __restrict__ Wf,
                                                      float* __restrict__ h) {
  __shared__ float mst[GH_NODES * 36];   // padded stride 36 (16B-aligned rows)
  int r = blockIdx.y;
  int n0 = blockIdx.x * GH_NODES;
  for (int t = threadIdx.x; t < GH_NODES * 32; t += 1024)
    mst[(t >> 5) * 36 + (t & 31)] = x[(size_t)n0 * 32 + t];
  int lane = threadIdx.x & 63, wv = threadIdx.x >> 6;
  int half = lane >> 5, l5 = lane & 31;
  const float* Wr = Wf + r * 1024;
  float w[32];
#pragma unroll
  for (int i = 0; i < 32; ++i) w[i] = Wr[i * 32 + l5];   // broadcast, L1-hot
  __syncthreads();
  float* hr = h + (size_t)r * N_NODES * 32;
#pragma unroll
  for (int k = 0; k < 5; ++k) {
    int nl = wv * 10 + k * 2 + half;                      // 2 nodes per wave
    const float4* mrow = (const float4*)&mst[nl * 36];
    float acc = 0.f;
#pragma unroll
    for (int i4 = 0; i4 < 8; ++i4) {
      float4 xx = mrow[i4];                               // LDS broadcast read
      acc = fmaf(xx.x, w[i4 * 4 + 0], acc);
      acc = fmaf(xx.y, w[i4 * 4 + 1], acc);
      acc = fmaf(xx.z, w[i4 * 4 + 2], acc);
      acc = fmaf(xx.w, w[i4 * 4 + 3], acc);
    }
    hr[(size_t)(n0 + nl) * 32 + l5] = acc;                // coalesced store
  }
}

// ------------- consume: branchless scaled gather-sum over edges ---------------
template <bool RELU>
__global__ __launch_bounds__(1024) void consume_kernel(const float* __restrict__ h,
                                                       const int* __restrict__ offs,
                                                       const uint2* __restrict__ eps,
                                                       const float* __restrict__ bias,
                                                       float* __restrict__ y) {
  int wv = threadIdx.x >> 6, lane = threadIdx.x & 63;
  int half = lane >> 5, l5 = lane & 31;
  int n = blockIdx.x * 16 + wv;          // grid exact: 6250*16 = 100000
  int b0 = offs[n * N_REL], b6 = offs[n * N_REL + 6];
  unsigned L4 = (unsigned)(l5 << 2);
  const char* hb = (const char*)h;
  float acc = 0.f;
  for (int chunk = b0; chunk < b6; chunk += 32) {
    int myp = chunk + l5;
    int cl = (myp < b6) ? myp : (b6 - 1);
    uint2 es = eps[cl];                  // one 8B coalesced load per 32 edges
    unsigned en = es.x;
    float sc = (myp < b6) ? __uint_as_float(es.y) : 0.f;  // tail-zero
    // branchless: all 16 gathers issue as one burst; clamped lanes hit a
    // single cached row and contribute 0 via sc.
#pragma unroll
    for (int e = 0; e < 32; e += 8) {
      unsigned q0 = __shfl(en, e + 0 + half, 32), q1 = __shfl(en, e + 2 + half, 32);
      unsigned q2 = __shfl(en, e + 4 + half, 32), q3 = __shfl(en, e + 6 + half, 32);
      float s0 = __shfl(sc, e + 0 + half, 32), s1 = __shfl(sc, e + 2 + half, 32);
      float s2 = __shfl(sc, e + 4 + half, 32), s3 = __shfl(sc, e + 6 + half, 32);
      float v0 = *(const float*)(hb + (q0 | L4));   // 4 full-wave gathers
      float v1 = *(const float*)(hb + (q1 | L4));
      float v2 = *(const float*)(hb + (q2 | L4));
      float v3 = *(const float*)(hb + (q3 | L4));
      acc = fmaf(s0, v0, acc);
      acc = fmaf(s1, v1, acc);
      acc = fmaf(s2, v2, acc);
      acc = fmaf(s3, v3, acc);
    }
  }
  acc += __shfl_xor(acc, 32);            // combine even/odd edge streams
  float res = acc + h[((size_t)6 * N_NODES + n) * 32 + l5] + bias[l5];  // root + bias
  if (RELU) res = fmaxf(res, 0.f);
  if (half == 0) y[(size_t)n * 32 + l5] = res;
}

extern "C" void kernel_launch(void* const* d_in, const int* in_sizes, int n_in,
                              void* d_out, int out_size, void* d_ws, size_t ws_size,
                              hipStream_t stream) {
  const float* embedding = (const float*)d_in[0];
  const int*   ei        = (const int*)d_in[1];     // [2, E]: src row, dst row
  const int*   et        = (const int*)d_in[2];
  const float* comp1  = (const float*)d_in[3];
  const float* basis1 = (const float*)d_in[4];
  const float* root1  = (const float*)d_in[5];
  const float* bias1  = (const float*)d_in[6];
  const float* comp2  = (const float*)d_in[7];
  const float* basis2 = (const float*)d_in[8];
  const float* root2  = (const float*)d_in[9];
  const float* bias2  = (const float*)d_in[10];
  float* out = (float*)d_out;

  const int* src = ei;
  const int* dst = ei + N_EDGES;

  float* ws = (float*)d_ws;
  size_t o = 0;
  float* Wf1 = ws + o; o += 7 * DIM * DIM;
  float* Wf2 = ws + o; o += 7 * DIM * DIM;
  float* x1  = ws + o; o += (size_t)N_NODES * DIM;
  float* h   = ws + o; o += (size_t)7 * N_NODES * DIM;   // 89.6 MB
  int* offs       = (int*)(ws + o); o += N_SEG + 1;
  o = (o + 1) & ~(size_t)1;              // 8B align for uint2
  uint2* eps      = (uint2*)(ws + o); o += 2 * (size_t)N_EDGES;
  int* cnt2       = (int*)(ws + o); o += SCAN_N;
  int* bOffs      = (int*)(ws + o); o += CB + 1;
  unsigned* packed = (unsigned*)h;       // alias: dead before gemm_h writes h

  hist2_kernel<<<NBLK, 1024, 0, stream>>>(dst, cnt2);
  scan2_kernel<<<1, 1024, 0, stream>>>(cnt2, bOffs);
  scatter2_kernel<<<NBLK, 1024, 0, stream>>>(src, dst, et, cnt2, packed);
  phaseB_kernel<<<CB, 1024, 0, stream>>>(packed, bOffs, offs, eps);
  weights_kernel<<<(2 * 7 * DIM * DIM + 255) / 256, 256, 0, stream>>>(
      comp1, basis1, root1, comp2, basis2, root2, Wf1, Wf2);

  // layer 1
  gemm_h_kernel<<<dim3(N_NODES / GH_NODES, 7), 1024, 0, stream>>>(embedding, Wf1, h);
  consume_kernel<true><<<N_NODES / 16, 1024, 0, stream>>>(h, offs, eps, bias1, x1);
  // layer 2
  gemm_h_kernel<<<dim3(N_NODES / GH_NODES, 7), 1024, 0, stream>>>(x1, Wf2, h);
  consume_kernel<false><<<N_NODES / 16, 1024, 0, stream>>>(h, offs, eps, bias2, out);
}

// Round 10
// 269.385 us; speedup vs baseline: 4.2387x; 1.0540x over previous
//
#include <hip/hip_runtime.h>

#define N_NODES 100000
#define N_EDGES 2500000
#define DIM 32
#define N_REL 6
#define N_BASES 4
#define N_SEG (N_NODES * N_REL)           // 600000 (dst,rel) segments
#define CB 196                             // coarse buckets: dst>>9
#define CNODES 512
#define CSEG (CNODES * N_REL)              // 3072 fine segments per coarse bucket
#define NBLK 256                           // partition blocks (1/CU)
#define SCAN_N (CB * NBLK)                 // 50176 = 1024 * 49
#define NITEM 49
#define GH_NODES 160                       // nodes per gemm_h block (100000 = 625*160)

// ---- pass 1: per-block bucket histogram -> cnt2[bucket*NBLK + block] ---------
__global__ __launch_bounds__(1024) void hist2_kernel(const int* __restrict__ dst,
                                                     int* __restrict__ cnt2) {
  __shared__ int h[CB];
  int t = threadIdx.x;
  for (int i = t; i < CB; i += 1024) h[i] = 0;
  __syncthreads();
  int per = (N_EDGES + NBLK - 1) / NBLK;
  int bstart = blockIdx.x * per;
  int bend = bstart + per; if (bend > N_EDGES) bend = N_EDGES;
  for (int e = bstart + t; e < bend; e += 1024)
    atomicAdd(&h[dst[e] >> 9], 1);
  __syncthreads();
  for (int i = t; i < CB; i += 1024)
    cnt2[i * NBLK + blockIdx.x] = h[i];
}

// ---- pass 2: exclusive scan of cnt2 (bucket-major) + bOffs -------------------
__global__ __launch_bounds__(1024) void scan2_kernel(int* __restrict__ cnt2,
                                                     int* __restrict__ bOffs) {
  __shared__ int ts[1024];
  int t = threadIdx.x;
  int base = t * NITEM;
  int loc[NITEM];
  int s = 0;
#pragma unroll
  for (int k = 0; k < NITEM; ++k) { loc[k] = s; s += cnt2[base + k]; }
  ts[t] = s;
  __syncthreads();
  for (int off = 1; off < 1024; off <<= 1) {
    int u = (t >= off) ? ts[t - off] : 0;
    __syncthreads();
    ts[t] += u;
    __syncthreads();
  }
  int excl = ts[t] - s;
#pragma unroll
  for (int k = 0; k < NITEM; ++k) {
    int idx = base + k;
    int v = excl + loc[k];
    cnt2[idx] = v;
    if ((idx & (NBLK - 1)) == 0) bOffs[idx / NBLK] = v;   // bucket boundary
  }
  if (t == 0) bOffs[CB] = N_EDGES;
}

// ---- pass 3: scatter into private (bucket,block) runs ------------------------
// payload: src(17b)<<12 | dst_low9<<3 | et(3b)
__global__ __launch_bounds__(1024) void scatter2_kernel(const int* __restrict__ src,
                                                        const int* __restrict__ dst,
                                                        const int* __restrict__ et,
                                                        const int* __restrict__ cnt2,
                                                        unsigned* __restrict__ packed) {
  __shared__ int sbase[CB];
  __shared__ int lcnt[CB];
  int t = threadIdx.x;
  for (int i = t; i < CB; i += 1024) {
    sbase[i] = cnt2[i * NBLK + blockIdx.x];
    lcnt[i] = 0;
  }
  __syncthreads();
  int per = (N_EDGES + NBLK - 1) / NBLK;
  int bstart = blockIdx.x * per;
  int bend = bstart + per; if (bend > N_EDGES) bend = N_EDGES;
  for (int e = bstart + t; e < bend; e += 1024) {
    int d = dst[e];
    int b = d >> 9;
    unsigned pl = ((unsigned)src[e] << 12) | ((unsigned)(d & 511) << 3) | (unsigned)et[e];
    int p = atomicAdd(&lcnt[b], 1);
    packed[sbase[b] + p] = pl;     // run private to this block -> clean lines
  }
}

// ------- phase B: per-coarse-bucket fine sort -> CSR + (ent,scl) pairs --------
// ent = byte offset into bf16 h: (rel*N + src) * 64
__global__ __launch_bounds__(1024) void phaseB_kernel(const unsigned* __restrict__ packed,
                                                      const int* __restrict__ bOffs,
                                                      int* __restrict__ offs,
                                                      uint2* __restrict__ eps) {
  __shared__ int scnt[CSEG];     // 12 KB
  __shared__ int sexcl[CSEG];    // 12 KB
  __shared__ float sinv[CSEG];   // 12 KB
  __shared__ int ssc[1024];      // 4 KB
  int b = blockIdx.x;
  int t = threadIdx.x;
  int beg = bOffs[b], end = bOffs[b + 1];
  for (int i = t; i < CSEG; i += 1024) scnt[i] = 0;
  __syncthreads();
  for (int i = beg + t; i < end; i += 1024) {
    unsigned pl = packed[i];
    int ls = (int)((pl >> 3) & 511u) * N_REL + (int)(pl & 7u);
    atomicAdd(&scnt[ls], 1);
  }
  __syncthreads();
  int b3 = t * 3;                // 3072 = 1024*3
  int a0 = scnt[b3], a1 = scnt[b3 + 1], a2 = scnt[b3 + 2];
  sinv[b3]     = a0 ? 1.f / (float)a0 : 0.f;
  sinv[b3 + 1] = a1 ? 1.f / (float)a1 : 0.f;
  sinv[b3 + 2] = a2 ? 1.f / (float)a2 : 0.f;
  int s = a0 + a1 + a2;
  ssc[t] = s;
  __syncthreads();
  for (int off = 1; off < 1024; off <<= 1) {
    int u = (t >= off) ? ssc[t - off] : 0;
    __syncthreads();
    ssc[t] += u;
    __syncthreads();
  }
  int excl = ssc[t] - s;
  sexcl[b3] = excl; sexcl[b3 + 1] = excl + a0; sexcl[b3 + 2] = excl + a0 + a1;
#pragma unroll
  for (int k = 0; k < 3; ++k) {
    int ls = b3 + k;
    int gseg = b * CSEG + ls;
    if (gseg < N_SEG) offs[gseg] = beg + sexcl[ls];
  }
  if (b == 0 && t == 0) offs[N_SEG] = N_EDGES;
  __syncthreads();
  scnt[b3] = 0; scnt[b3 + 1] = 0; scnt[b3 + 2] = 0;
  __syncthreads();
  for (int i = beg + t; i < end; i += 1024) {
    unsigned pl = packed[i];
    int ls = (int)((pl >> 3) & 511u) * N_REL + (int)(pl & 7u);
    int p = atomicAdd(&scnt[ls], 1);
    int pos = beg + sexcl[ls] + p;
    unsigned sr = pl >> 12, rr = pl & 7u;
    uint2 v;
    v.x = (rr * (unsigned)N_NODES + sr) << 6;   // byte offset into bf16 h
    v.y = __float_as_uint(sinv[ls]);            // 1/count (mean weight)
    eps[pos] = v;
  }
}

// ------------- weights: Wf[r][i][o], r=0..5 basis-combined, r=6 root ----------
__global__ void weights_kernel(const float* __restrict__ comp1, const float* __restrict__ basis1,
                               const float* __restrict__ root1,
                               const float* __restrict__ comp2, const float* __restrict__ basis2,
                               const float* __restrict__ root2,
                               float* __restrict__ Wf1, float* __restrict__ Wf2) {
  int idx = blockIdx.x * blockDim.x + threadIdx.x;
  if (idx >= 2 * 7 * DIM * DIM) return;
  int layer = idx / (7 * DIM * DIM);
  int rem = idx - layer * (7 * DIM * DIM);
  int r = rem / (DIM * DIM);
  int io = rem - r * (DIM * DIM);        // i*32+o
  const float* comp  = layer ? comp2  : comp1;
  const float* basis = layer ? basis2 : basis1;
  const float* root  = layer ? root2  : root1;
  float val;
  if (r < 6) {
    val = 0.f;
#pragma unroll
    for (int bb = 0; bb < N_BASES; ++bb)
      val += comp[r * N_BASES + bb] * basis[bb * DIM * DIM + io];
  } else {
    val = root[io];
  }
  (layer ? Wf2 : Wf1)[rem] = val;
}

// ---- RNE float -> bf16 (bit trick, matches __float2bfloat16 for normals) -----
__device__ __forceinline__ unsigned short f2bf(float f) {
  unsigned u = __float_as_uint(f);
  unsigned rb = ((u >> 16) & 1u) + 0x7fffu;      // round-to-nearest-even
  return (unsigned short)((u + rb) >> 16);
}

// ------------- h precompute: h[r][n][o] (bf16) = sum_i x[n][i]*Wf[r][i][o] ----
__global__ __launch_bounds__(1024) void gemm_h_kernel(const float* __restrict__ x,
                                                      const float* __restrict__ Wf,
                                                      unsigned short* __restrict__ h) {
  __shared__ float mst[GH_NODES * 36];   // padded stride 36 (16B-aligned rows)
  int r = blockIdx.y;
  int n0 = blockIdx.x * GH_NODES;
  for (int t = threadIdx.x; t < GH_NODES * 32; t += 1024)
    mst[(t >> 5) * 36 + (t & 31)] = x[(size_t)n0 * 32 + t];
  int lane = threadIdx.x & 63, wv = threadIdx.x >> 6;
  int half = lane >> 5, l5 = lane & 31;
  const float* Wr = Wf + r * 1024;
  float w[32];
#pragma unroll
  for (int i = 0; i < 32; ++i) w[i] = Wr[i * 32 + l5];   // broadcast, L1-hot
  __syncthreads();
  unsigned short* hr = h + (size_t)r * N_NODES * 32;
#pragma unroll
  for (int k = 0; k < 5; ++k) {
    int nl = wv * 10 + k * 2 + half;                      // 2 nodes per wave
    const float4* mrow = (const float4*)&mst[nl * 36];
    float acc = 0.f;
#pragma unroll
    for (int i4 = 0; i4 < 8; ++i4) {
      float4 xx = mrow[i4];                               // LDS broadcast read
      acc = fmaf(xx.x, w[i4 * 4 + 0], acc);
      acc = fmaf(xx.y, w[i4 * 4 + 1], acc);
      acc = fmaf(xx.z, w[i4 * 4 + 2], acc);
      acc = fmaf(xx.w, w[i4 * 4 + 3], acc);
    }
    hr[(size_t)(n0 + nl) * 32 + l5] = f2bf(acc);          // coalesced 2B store
  }
}

// ------------- consume: bf16 gather-sum, 4 edge-rows per gather instr ---------
// lane = q*16 + l4 (q=0..3): handles features {2*l4, 2*l4+1} of edge (e + q mod 4)
template <bool RELU>
__global__ __launch_bounds__(1024) void consume_kernel(const unsigned short* __restrict__ h,
                                                       const int* __restrict__ offs,
                                                       const uint2* __restrict__ eps,
                                                       const float* __restrict__ bias,
                                                       float* __restrict__ y) {
  int wv = threadIdx.x >> 6, lane = threadIdx.x & 63;
  int l5 = lane & 31;                    // eps slot
  int q = lane >> 4;                     // quarter 0..3 (edge sub-index)
  int l4 = lane & 15;                    // feature pair index
  int n = blockIdx.x * 16 + wv;          // grid exact: 6250*16 = 100000
  int b0 = offs[n * N_REL], b6 = offs[n * N_REL + 6];
  unsigned F4 = (unsigned)(l4 << 2);     // byte offset of feature pair in 64B row
  const char* hb = (const char*)h;
  float acc0 = 0.f, acc1 = 0.f;
  for (int chunk = b0; chunk < b6; chunk += 32) {
    int myp = chunk + l5;
    int cl = (myp < b6) ? myp : (b6 - 1);
    uint2 es = eps[cl];                  // one 8B coalesced load per 32 edges
    unsigned en = es.x;
    float sc = (myp < b6) ? __uint_as_float(es.y) : 0.f;  // tail-zero
#pragma unroll
    for (int e = 0; e < 32; e += 8) {
      // 2 gather instrs cover 8 edges (4 rows x 16 lanes each)
      unsigned q0 = __shfl(en, e + 0 + q, 32);      // my edge's row offset
      unsigned q1 = __shfl(en, e + 4 + q, 32);
      float s0 = __shfl(sc, e + 0 + q, 32);
      float s1 = __shfl(sc, e + 4 + q, 32);
      unsigned v0 = *(const unsigned*)(hb + (q0 | F4));   // 2 bf16 features
      unsigned v1 = *(const unsigned*)(hb + (q1 | F4));
      acc0 = fmaf(s0, __uint_as_float(v0 << 16), acc0);           // even feat
      acc1 = fmaf(s0, __uint_as_float(v0 & 0xffff0000u), acc1);   // odd feat
      acc0 = fmaf(s1, __uint_as_float(v1 << 16), acc0);
      acc1 = fmaf(s1, __uint_as_float(v1 & 0xffff0000u), acc1);
    }
  }
  // combine quarters (each quarter summed a different residue class of edges)
  acc0 += __shfl_xor(acc0, 16);
  acc0 += __shfl_xor(acc0, 32);
  acc1 += __shfl_xor(acc1, 16);
  acc1 += __shfl_xor(acc1, 32);
  // root row (bf16) + bias
  unsigned rv = *(const unsigned*)(hb + ((((size_t)6 * N_NODES + n) << 6)) + F4);
  float r0 = acc0 + __uint_as_float(rv << 16) + bias[2 * l4];
  float r1 = acc1 + __uint_as_float(rv & 0xffff0000u) + bias[2 * l4 + 1];
  if (RELU) { r0 = fmaxf(r0, 0.f); r1 = fmaxf(r1, 0.f); }
  if (lane < 16) {
    float2 st; st.x = r0; st.y = r1;
    *(float2*)(y + (size_t)n * 32 + 2 * l4) = st;
  }
}

extern "C" void kernel_launch(void* const* d_in, const int* in_sizes, int n_in,
                              void* d_out, int out_size, void* d_ws, size_t ws_size,
                              hipStream_t stream) {
  const float* embedding = (const float*)d_in[0];
  const int*   ei        = (const int*)d_in[1];     // [2, E]: src row, dst row
  const int*   et        = (const int*)d_in[2];
  const float* comp1  = (const float*)d_in[3];
  const float* basis1 = (const float*)d_in[4];
  const float* root1  = (const float*)d_in[5];
  const float* bias1  = (const float*)d_in[6];
  const float* comp2  = (const float*)d_in[7];
  const float* basis2 = (const float*)d_in[8];
  const float* root2  = (const float*)d_in[9];
  const float* bias2  = (const float*)d_in[10];
  float* out = (float*)d_out;

  const int* src = ei;
  const int* dst = ei + N_EDGES;

  float* ws = (float*)d_ws;
  size_t o = 0;
  float* Wf1 = ws + o; o += 7 * DIM * DIM;
  float* Wf2 = ws + o; o += 7 * DIM * DIM;
  float* x1  = ws + o; o += (size_t)N_NODES * DIM;
  unsigned short* h = (unsigned short*)(ws + o);
  o += (size_t)7 * N_NODES * DIM / 2 + 16;               // bf16 h: 44.8 MB
  int* offs       = (int*)(ws + o); o += N_SEG + 1;
  o = (o + 1) & ~(size_t)1;              // 8B align for uint2
  uint2* eps      = (uint2*)(ws + o); o += 2 * (size_t)N_EDGES;
  int* cnt2       = (int*)(ws + o); o += SCAN_N;
  int* bOffs      = (int*)(ws + o); o += CB + 1;
  unsigned* packed = (unsigned*)h;       // alias: dead before gemm_h writes h

  hist2_kernel<<<NBLK, 1024, 0, stream>>>(dst, cnt2);
  scan2_kernel<<<1, 1024, 0, stream>>>(cnt2, bOffs);
  scatter2_kernel<<<NBLK, 1024, 0, stream>>>(src, dst, et, cnt2, packed);
  phaseB_kernel<<<CB, 1024, 0, stream>>>(packed, bOffs, offs, eps);
  weights_kernel<<<(2 * 7 * DIM * DIM + 255) / 256, 256, 0, stream>>>(
      comp1, basis1, root1, comp2, basis2, root2, Wf1, Wf2);

  // layer 1
  gemm_h_kernel<<<dim3(N_NODES / GH_NODES, 7), 1024, 0, stream>>>(embedding, Wf1, h);
  consume_kernel<true><<<N_NODES / 16, 1024, 0, stream>>>(h, offs, eps, bias1, x1);
  // layer 2
  gemm_h_kernel<<<dim3(N_NODES / GH_NODES, 7), 1024, 0, stream>>>(x1, Wf2, h);
  consume_kernel<false><<<N_NODES / 16, 1024, 0, stream>>>(h, offs, eps, bias2, out);
}